// Round 9
// baseline (344.698 us; speedup 1.0000x reference)
//
#include <hip/hip_runtime.h>

#define NP 20000
#define NC 80000
#define NN 100000
#define NE 1600000
#define HD 128
#define MAXDEG 64
#define BKT 391   // buckets of 256 nodes
#define BINB 391  // bin blocks, 4096 edges each

// Timing model (R7/R8 fit): ~107 us FIXED harness overhead per iteration.
// Budget at R8=327.5: C=107 | agg_sage 2x84.5 | graph chain ~51.
// agg_sage = phase1 gather 57 (path plateau ~7.3 TB/s useful, MLP-proven
// saturated) + phase2 27.5 (latency chain on hr/W loads after the barrier).

typedef unsigned short ushort_t;
typedef unsigned int uint_t;

typedef __attribute__((ext_vector_type(8))) short bf16x8;
typedef __attribute__((ext_vector_type(4))) float f32x4;

// fp32 -> bf16 RNE
__device__ __forceinline__ ushort_t f2bf(float f) {
  uint_t u = __builtin_bit_cast(uint_t, f);
  u = (u + 0x7FFF + ((u >> 16) & 1)) >> 16;
  return (ushort_t)u;
}
__device__ __forceinline__ float bf_lo(uint_t p) {
  return __builtin_bit_cast(float, p << 16);
}
__device__ __forceinline__ float bf_hi(uint_t p) {
  return __builtin_bit_cast(float, p & 0xFFFF0000u);
}
__device__ __forceinline__ uint4 pack8(float4 lo, float4 hi) {
  ushort_t t[8];
  t[0] = f2bf(lo.x); t[1] = f2bf(lo.y); t[2] = f2bf(lo.z); t[3] = f2bf(lo.w);
  t[4] = f2bf(hi.x); t[5] = f2bf(hi.y); t[6] = f2bf(hi.z); t[7] = f2bf(hi.w);
  return *(uint4*)t;
}

// pack one task of W (fp32, K x 128) into bf16 B-fragment order, K padded
// with zeros to KB*32. task in [0, 8*KB*64). P idx = task*8 + j.
__device__ __forceinline__ void pack_tile(const float* __restrict__ W,
                                          ushort_t* __restrict__ P, int KF,
                                          int KB, int task) {
  int t = task / (KB * 64);
  int rem = task - t * KB * 64;
  int kb = rem >> 6;
  int lane = rem & 63;
  int k0 = kb * 32 + ((lane >> 4) << 3);
  int c = t * 16 + (lane & 15);
  ushort_t tmp[8];
#pragma unroll
  for (int j = 0; j < 8; ++j) {
    int k = k0 + j;
    tmp[j] = (k < KF) ? f2bf(W[(size_t)k * HD + c]) : (ushort_t)0;
  }
  *(uint4*)(P + (size_t)task * 8) = *(uint4*)tmp;
}

// ---------------- prep: per-block bucket histogram + all W packs ----------
#define PACKB 46  // 4x8 (sage) + 8 (Wcomp K=128) + 6 (Wpol K=96)
__global__ __launch_bounds__(256) void prep_k(
    const int* __restrict__ dst, int* __restrict__ hist2t,
    const float* __restrict__ Wl1, const float* __restrict__ Wr1,
    const float* __restrict__ Wl2, const float* __restrict__ Wr2,
    const float* __restrict__ W_comp, const float* __restrict__ W_pol,
    ushort_t* __restrict__ wl1p, ushort_t* __restrict__ wr1p,
    ushort_t* __restrict__ wl2p, ushort_t* __restrict__ wr2p,
    ushort_t* __restrict__ wcompp, ushort_t* __restrict__ wpolp) {
  __shared__ int hist[BKT];
  int blk = blockIdx.x;
  int tid = threadIdx.x;
  if (blk < BINB) {
    for (int t = tid; t < BKT; t += 256) hist[t] = 0;
    __syncthreads();
    int base = blk * 4096;
#pragma unroll
    for (int q = 0; q < 16; ++q) {
      int e = base + q * 256 + tid;
      if (e < NE) atomicAdd(&hist[dst[e] >> 8], 1);
    }
    __syncthreads();
    for (int t = tid; t < BKT; t += 256)
      hist2t[(size_t)t * BINB + blk] = hist[t];
    return;
  }
  int pb = blk - BINB;
  if (pb < 8) pack_tile(Wl1, wl1p, 128, 4, pb * 256 + tid);
  else if (pb < 16) pack_tile(Wr1, wr1p, 128, 4, (pb - 8) * 256 + tid);
  else if (pb < 24) pack_tile(Wl2, wl2p, 128, 4, (pb - 16) * 256 + tid);
  else if (pb < 32) pack_tile(Wr2, wr2p, 128, 4, (pb - 24) * 256 + tid);
  else if (pb < 40) pack_tile(W_comp, wcompp, 112, 4, (pb - 32) * 256 + tid);
  else pack_tile(W_pol, wpolp, 72, 3, (pb - 40) * 256 + tid);
}

// ------- scanA: per-bucket exclusive prefix over blocks (wave scan) -------
__global__ __launch_bounds__(64) void scanA_k(int* __restrict__ hist2t,
                                              int* __restrict__ bcnt) {
  int t = blockIdx.x;
  int lane = threadIdx.x;
  int* base = hist2t + (size_t)t * BINB;
  int carry = 0;
  for (int c = 0; c < 7; ++c) {  // 7*64 = 448 >= BINB
    int i = c * 64 + lane;
    int orig = (i < BINB) ? base[i] : 0;
    int v = orig;
#pragma unroll
    for (int off = 1; off < 64; off <<= 1) {
      int u = __shfl_up(v, off);
      if (lane >= off) v += u;
    }
    if (i < BINB) base[i] = v - orig + carry;
    carry += __shfl(v, 63);
  }
  if (lane == 0) bcnt[t] = carry;
}

// ---------------- scanB: exclusive scan of bucket totals ----------------
__global__ __launch_bounds__(512) void scan_k(const int* __restrict__ bcnt,
                                              int* __restrict__ bstart) {
  __shared__ int s[512];
  int t = threadIdx.x;
  int v = (t < BKT) ? bcnt[t] : 0;
  s[t] = v;
  __syncthreads();
  for (int off = 1; off < 512; off <<= 1) {
    int x = (t >= off) ? s[t - off] : 0;
    __syncthreads();
    s[t] += x;
    __syncthreads();
  }
  if (t < BKT) bstart[t] = s[t] - v;
}

// ---------------- bin edges + MFMA encoders (fused, independent) -----------
// R7 lesson: keep the staged LDS sort (dropping it cost +9 us via
// uncoalesced 4B ebuf scatters). Deterministic gbase (R4, no bfill atomics).
#define COMP_E (NC / 128)        // 625 blocks, 128 nodes each
#define POL_E ((NP + 127) / 128) // 157
__global__ __launch_bounds__(512) void bin_enc_k(
    const int* __restrict__ src, const int* __restrict__ dst,
    const int* __restrict__ bstart, const int* __restrict__ hist2t,
    uint_t* __restrict__ ebuf,
    const float* __restrict__ x_comp, const int* __restrict__ sec,
    const int* __restrict__ ind, const float* __restrict__ semb,
    const float* __restrict__ iemb, const ushort_t* __restrict__ wcompp,
    const float* __restrict__ b_comp,
    const float* __restrict__ x_pol, const int* __restrict__ sidx,
    const float* __restrict__ stemb, const ushort_t* __restrict__ wpolp,
    const float* __restrict__ b_pol,
    ushort_t* __restrict__ h0) {
  __shared__ int hist[BKT];
  __shared__ int lscan[BKT];
  __shared__ int gbase[BKT];
  __shared__ int sv[512];
  __shared__ uint2 stage[4096];
  int blk = blockIdx.x;
  int tid = threadIdx.x;

  if (blk < BINB) {
    // ---- counting-sort 4096 edges into bucket-grouped ebuf ----
    for (int t = tid; t < BKT; t += 512) hist[t] = 0;
    __syncthreads();
    int base = blk * 4096;
    int cntE = min(4096, NE - base);
    int ss[8], dd[8], rr[8];
#pragma unroll
    for (int q = 0; q < 8; ++q) {
      int e = base + q * 512 + tid;
      if (e < NE) {
        dd[q] = dst[e];
        ss[q] = src[e];
        rr[q] = atomicAdd(&hist[dd[q] >> 8], 1);
      } else {
        dd[q] = -1;
      }
    }
    __syncthreads();
    int hv = (tid < BKT) ? hist[tid] : 0;
    sv[tid] = hv;
    __syncthreads();
    for (int off = 1; off < 512; off <<= 1) {
      int x = (tid >= off) ? sv[tid - off] : 0;
      __syncthreads();
      sv[tid] += x;
      __syncthreads();
    }
    if (tid < BKT) {
      lscan[tid] = sv[tid] - hv;
      gbase[tid] = bstart[tid] + hist2t[(size_t)tid * BINB + blk];
    }
    __syncthreads();
#pragma unroll
    for (int q = 0; q < 8; ++q) {
      if (dd[q] >= 0) {
        int bb = dd[q] >> 8;
        stage[lscan[bb] + rr[q]] = make_uint2((uint_t)ss[q], (uint_t)dd[q]);
      }
    }
    __syncthreads();
    for (int j = tid; j < cntE; j += 512) {
      uint2 v = stage[j];
      int bb = v.y >> 8;
      ebuf[gbase[bb] + (j - lscan[bb])] = (v.x << 8) | (v.y & 255u);
    }
    return;
  }
  int lane = tid & 63;
  int wv = tid >> 6;
  int n16 = lane & 15, quad = lane >> 4;
  if (blk < BINB + COMP_E) {
    // ---- comp encoder via MFMA: h = relu([x|sec|ind|0pad] @ Wc + bc) ----
    int rowbase = (blk - BINB) * 128 + wv * 16;
    int node = rowbase + n16;
    const float4* xr = (const float4*)(x_comp + (size_t)node * 96);
    uint4 a[4];
#pragma unroll
    for (int kb = 0; kb < 3; ++kb)
      a[kb] = pack8(xr[kb * 8 + quad * 2], xr[kb * 8 + quad * 2 + 1]);
    if (quad == 0) {
      const float4* er = (const float4*)(semb + (size_t)sec[node] * 8);
      a[3] = pack8(er[0], er[1]);
    } else if (quad == 1) {
      const float4* er = (const float4*)(iemb + (size_t)ind[node] * 8);
      a[3] = pack8(er[0], er[1]);
    } else {
      a[3] = make_uint4(0, 0, 0, 0);
    }
    const bf16x8* W = (const bf16x8*)wcompp;
    ushort_t* hb = h0 + (size_t)NP * HD;
#pragma unroll
    for (int t = 0; t < 8; ++t) {
      float bias = b_comp[t * 16 + n16];
      f32x4 acc = {bias, bias, bias, bias};
#pragma unroll
      for (int kb = 0; kb < 4; ++kb)
        acc = __builtin_amdgcn_mfma_f32_16x16x32_bf16(
            __builtin_bit_cast(bf16x8, a[kb]), W[(t * 4 + kb) * 64 + lane],
            acc, 0, 0, 0);
      int r0 = rowbase + quad * 4;
      int c = t * 16 + n16;
#pragma unroll
      for (int r = 0; r < 4; ++r)
        hb[(size_t)(r0 + r) * HD + c] = f2bf(fmaxf(acc[r], 0.f));
    }
    return;
  }
  {
    // ---- pol encoder via MFMA: h = relu([x|state|0pad] @ Wp + bp) ----
    int rowbase = (blk - BINB - COMP_E) * 128 + wv * 16;
    if (rowbase >= NP) return;
    int node = rowbase + n16;
    const float4* xr = (const float4*)(x_pol + (size_t)node * 64);
    uint4 a[3];
#pragma unroll
    for (int kb = 0; kb < 2; ++kb)
      a[kb] = pack8(xr[kb * 8 + quad * 2], xr[kb * 8 + quad * 2 + 1]);
    if (quad == 0) {
      const float4* er = (const float4*)(stemb + (size_t)sidx[node] * 8);
      a[2] = pack8(er[0], er[1]);
    } else {
      a[2] = make_uint4(0, 0, 0, 0);
    }
    const bf16x8* W = (const bf16x8*)wpolp;
#pragma unroll
    for (int t = 0; t < 8; ++t) {
      float bias = b_pol[t * 16 + n16];
      f32x4 acc = {bias, bias, bias, bias};
#pragma unroll
      for (int kb = 0; kb < 3; ++kb)
        acc = __builtin_amdgcn_mfma_f32_16x16x32_bf16(
            __builtin_bit_cast(bf16x8, a[kb]), W[(t * 3 + kb) * 64 + lane],
            acc, 0, 0, 0);
      int r0 = rowbase + quad * 4;
      int c = t * 16 + n16;
#pragma unroll
      for (int r = 0; r < 4; ++r)
        h0[(size_t)(r0 + r) * HD + c] = f2bf(fmaxf(acc[r], 0.f));
    }
  }
}

// ---------------- build: per-bucket L2-local CSR fill ----------------
__global__ __launch_bounds__(512) void build_k(const uint_t* __restrict__ ebuf,
                                               const int* __restrict__ bstart,
                                               const int* __restrict__ bcnt,
                                               int* __restrict__ col,
                                               int* __restrict__ cnt) {
  __shared__ int lcnt[256];
  int tid = threadIdx.x;
  int b = blockIdx.x;
  if (tid < 256) lcnt[tid] = 0;
  __syncthreads();
  int st = bstart[b];
  int cb = bcnt[b];
  for (int off = tid; off < cb; off += 512) {
    uint_t v = ebuf[st + off];
    int nl = v & 255u;
    int p = atomicAdd(&lcnt[nl], 1);
    if (p < MAXDEG) col[(size_t)((b << 8) | nl) * MAXDEG + p] = (int)(v >> 8);
  }
  __syncthreads();
  if (tid < 256) {
    int node = (b << 8) + tid;
    if (node < NN) cnt[node] = lcnt[tid];
  }
}

// ---------------- fused aggregate + SAGE (m never touches HBM) ------------
// R8 + phase-2 operand hoist: the hr (own-h) rows and bias are loaded at
// kernel entry, before the gather loop -- their ~600cyc L3 latency completes
// under phase 1's 57us instead of serializing after the barrier. Phase 2 is
// then LDS + L2-hot W + MFMA only. (R8 counters: phase2 ~27.5us was a
// dependent-load latency chain -- 3% MFMA, 1.9 TB/s, not BW-bound.)
__global__ __launch_bounds__(512) void agg_sage_k(
    const ushort_t* __restrict__ hbf, const int* __restrict__ cnt,
    const int* __restrict__ col, const ushort_t* __restrict__ Wlp,
    const float* __restrict__ bl, const ushort_t* __restrict__ Wrp,
    float* __restrict__ outf, ushort_t* __restrict__ outb, int relu) {
  __shared__ __align__(16) ushort_t lm[16][136];  // +8 pad
  const uint4* hrow = (const uint4*)hbf;  // row = 16 uint4
  int tid = threadIdx.x;
  int lane = tid & 63;
  int wv = tid >> 6;                // 0..7
  int rowbase = blockIdx.x * 16;    // grid = NN/16 = 6250
  int grp = lane >> 4;  // 0..3: edge subgroup / quad
  int l16 = lane & 15;  // 16B chunk within row / n16

  // ---- phase-2 operand prefetch (no deps on phase 1; hides under gather) --
  int t2 = wv;  // each wave owns one 16-col output slab in phase 2
  const uint4* hr = (const uint4*)(hbf + (size_t)(rowbase + l16) * HD);
  uint4 ah[4];
#pragma unroll
  for (int kb = 0; kb < 4; ++kb) ah[kb] = hr[kb * 4 + grp];
  float bias = bl[t2 * 16 + l16];

  // ---- phase 1: 2 nodes/wave gather (proven structure, 8 loads in flight) -
  int iA = rowbase + wv * 2;
  int iB = iA + 1;
  int dA = min(cnt[iA], MAXDEG);
  int dB = min(cnt[iB], MAXDEG);
  float accA[8] = {0.f, 0.f, 0.f, 0.f, 0.f, 0.f, 0.f, 0.f};
  float accB[8] = {0.f, 0.f, 0.f, 0.f, 0.f, 0.f, 0.f, 0.f};
  int mycA = (lane < dA) ? col[(size_t)iA * MAXDEG + lane] : 0;
  int mycB = (lane < dB) ? col[(size_t)iB * MAXDEG + lane] : 0;
  int nch = (max(dA, dB) + 15) >> 4;
  for (int ch = 0; ch < nch; ++ch) {
    int j0 = ch * 16;
    uint4 pA[4], pB[4];
    bool vA[4], vB[4];
#pragma unroll
    for (int q = 0; q < 4; ++q) {
      int e = j0 + q * 4 + grp;
      vA[q] = e < dA;
      int s = __shfl(mycA, vA[q] ? e : 0);
      pA[q] = hrow[(size_t)s * 16 + l16];
    }
#pragma unroll
    for (int q = 0; q < 4; ++q) {
      int e = j0 + q * 4 + grp;
      vB[q] = e < dB;
      int s = __shfl(mycB, vB[q] ? e : 0);
      pB[q] = hrow[(size_t)s * 16 + l16];
    }
#pragma unroll
    for (int q = 0; q < 4; ++q) {
      if (vA[q]) {
        accA[0] += bf_lo(pA[q].x); accA[1] += bf_hi(pA[q].x);
        accA[2] += bf_lo(pA[q].y); accA[3] += bf_hi(pA[q].y);
        accA[4] += bf_lo(pA[q].z); accA[5] += bf_hi(pA[q].z);
        accA[6] += bf_lo(pA[q].w); accA[7] += bf_hi(pA[q].w);
      }
      if (vB[q]) {
        accB[0] += bf_lo(pB[q].x); accB[1] += bf_hi(pB[q].x);
        accB[2] += bf_lo(pB[q].y); accB[3] += bf_hi(pB[q].y);
        accB[4] += bf_lo(pB[q].z); accB[5] += bf_hi(pB[q].z);
        accB[6] += bf_lo(pB[q].w); accB[7] += bf_hi(pB[q].w);
      }
    }
  }
#pragma unroll
  for (int k = 0; k < 8; ++k) {
    accA[k] += __shfl_xor(accA[k], 16);
    accA[k] += __shfl_xor(accA[k], 32);
    accB[k] += __shfl_xor(accB[k], 16);
    accB[k] += __shfl_xor(accB[k], 32);
  }
  if (grp == 0) {
    float inv = 1.f / (float)max(dA, 1);
    ushort_t t[8];
#pragma unroll
    for (int k = 0; k < 8; ++k) t[k] = f2bf(accA[k] * inv);
    *(uint4*)&lm[wv * 2][l16 * 8] = *(uint4*)t;
  } else if (grp == 1) {
    float inv = 1.f / (float)max(dB, 1);
    ushort_t t[8];
#pragma unroll
    for (int k = 0; k < 8; ++k) t[k] = f2bf(accB[k] * inv);
    *(uint4*)&lm[wv * 2 + 1][l16 * 8] = *(uint4*)t;
  }
  __syncthreads();

  // ---- phase 2: out[:, wv*16:(wv+1)*16] = [relu](m@Wl + bl + h@Wr) ----
  int n16 = l16, quad = grp;
  uint4 am[4];
#pragma unroll
  for (int kb = 0; kb < 4; ++kb)
    am[kb] = *(const uint4*)&lm[n16][(kb * 4 + quad) * 8];
  const bf16x8* WL = (const bf16x8*)Wlp;
  const bf16x8* WR = (const bf16x8*)Wrp;
  f32x4 acc = {bias, bias, bias, bias};
#pragma unroll
  for (int kb = 0; kb < 4; ++kb)
    acc = __builtin_amdgcn_mfma_f32_16x16x32_bf16(
        __builtin_bit_cast(bf16x8, am[kb]), WL[(t2 * 4 + kb) * 64 + lane],
        acc, 0, 0, 0);
#pragma unroll
  for (int kb = 0; kb < 4; ++kb)
    acc = __builtin_amdgcn_mfma_f32_16x16x32_bf16(
        __builtin_bit_cast(bf16x8, ah[kb]), WR[(t2 * 4 + kb) * 64 + lane],
        acc, 0, 0, 0);
  int r0 = rowbase + quad * 4;
  int c = t2 * 16 + n16;
#pragma unroll
  for (int r = 0; r < 4; ++r) {
    float v = acc[r];
    if (relu) v = fmaxf(v, 0.f);
    if (outb)
      outb[(size_t)(r0 + r) * HD + c] = f2bf(v);
    else
      outf[(size_t)(r0 + r) * HD + c] = v;
  }
}

extern "C" void kernel_launch(void* const* d_in, const int* in_sizes, int n_in,
                              void* d_out, int out_size, void* d_ws,
                              size_t ws_size, hipStream_t stream) {
  const float* x_pol = (const float*)d_in[0];
  const int* pol_state_idx = (const int*)d_in[1];
  const float* x_comp = (const float*)d_in[2];
  const int* comp_sector = (const int*)d_in[3];
  const int* comp_ind = (const int*)d_in[4];
  const float* state_emb = (const float*)d_in[6];
  const float* sector_emb = (const float*)d_in[7];
  const float* ind_emb = (const float*)d_in[8];
  const float* W_pol = (const float*)d_in[9];
  const float* b_pol = (const float*)d_in[10];
  const float* W_comp = (const float*)d_in[11];
  const float* b_comp = (const float*)d_in[12];
  const float* Wl1 = (const float*)d_in[13];
  const float* bl1 = (const float*)d_in[14];
  const float* Wr1 = (const float*)d_in[15];
  const float* Wl2 = (const float*)d_in[16];
  const float* bl2 = (const float*)d_in[17];
  const float* Wr2 = (const float*)d_in[18];

  const int* src = (const int*)d_in[5];         // edge_index[0]
  const int* dst = ((const int*)d_in[5]) + NE;  // edge_index[1]

  // ws: h0_bf | h1_bf | col[NN*64] | ebuf[NE] | cnt[NN] |
  //     packed W x6 | bcnt | bstart | hist2t[391*391]   ~85 MB
  const size_t HBYTES = (size_t)NN * HD * sizeof(ushort_t);  // 25.6 MB
  char* ws = (char*)d_ws;
  ushort_t* h0_bf = (ushort_t*)ws;
  ushort_t* h1_bf = (ushort_t*)(ws + HBYTES);
  int* col = (int*)(ws + 2 * HBYTES);
  uint_t* ebuf = (uint_t*)(col + (size_t)NN * MAXDEG);
  int* cnt = (int*)(ebuf + NE);
  ushort_t* wl1p = (ushort_t*)(cnt + NN);  // 16384 elems each (K=128)
  ushort_t* wr1p = wl1p + 16384;
  ushort_t* wl2p = wr1p + 16384;
  ushort_t* wr2p = wl2p + 16384;
  ushort_t* wcompp = wr2p + 16384;   // 16384 (K padded to 128)
  ushort_t* wpolp = wcompp + 16384;  // 12288 (K padded to 96)
  int* bcnt = (int*)(wpolp + 12288);
  int* bstart = bcnt + BKT;
  int* hist2t = bstart + BKT;  // [BKT][BINB] = 611 KB

  float* out_f = (float*)d_out;

  // chain: per-block hist (no atomics) -> per-bucket block-prefix scan ->
  // bucket-total scan -> deterministic staged bin -> build
  prep_k<<<BINB + PACKB, 256, 0, stream>>>(dst, hist2t, Wl1, Wr1, Wl2, Wr2,
                                           W_comp, W_pol, wl1p, wr1p, wl2p,
                                           wr2p, wcompp, wpolp);
  scanA_k<<<BKT, 64, 0, stream>>>(hist2t, bcnt);
  scan_k<<<1, 512, 0, stream>>>(bcnt, bstart);
  bin_enc_k<<<BINB + COMP_E + POL_E, 512, 0, stream>>>(
      src, dst, bstart, hist2t, ebuf, x_comp, comp_sector, comp_ind,
      sector_emb, ind_emb, wcompp, b_comp, x_pol, pol_state_idx, state_emb,
      wpolp, b_pol, h0_bf);
  build_k<<<BKT, 512, 0, stream>>>(ebuf, bstart, bcnt, col, cnt);

  // layer 1: h1 = relu(mean-aggr(h0)@Wl1 + bl1 + h0@Wr1)  (bf16 out)
  agg_sage_k<<<NN / 16, 512, 0, stream>>>(h0_bf, cnt, col, wl1p, bl1, wr1p,
                                          nullptr, h1_bf, 1);
  // layer 2: out = mean-aggr(h1)@Wl2 + bl2 + h1@Wr2  (fp32 out)
  agg_sage_k<<<NN / 16, 512, 0, stream>>>(h1_bf, cnt, col, wl2p, bl2, wr2p,
                                          out_f, nullptr, 0);
}

// Round 10
// 296.035 us; speedup vs baseline: 1.1644x; 1.1644x over previous
//
#include <hip/hip_runtime.h>

#define NP 20000
#define NC 80000
#define NN 100000
#define NE 1600000
#define HD 128
#define MAXDEG 64
#define BKT 391   // buckets of 256 nodes
#define BINB 391  // bin blocks, 4096 edges each

// Timing model (R7/R8 fit): ~107 us FIXED harness overhead per iteration.
// Budget at R8=327.5: C=107 | agg_sage 2x84.5 | graph chain ~51.
// R9 lesson: register-hoisting phase-2 operands across the gather loop costs
// occupancy (VGPR 36->44, occ 58->41%, -9 us). Stage via LDS instead.

typedef unsigned short ushort_t;
typedef unsigned int uint_t;

typedef __attribute__((ext_vector_type(8))) short bf16x8;
typedef __attribute__((ext_vector_type(4))) float f32x4;

// fp32 -> bf16 RNE
__device__ __forceinline__ ushort_t f2bf(float f) {
  uint_t u = __builtin_bit_cast(uint_t, f);
  u = (u + 0x7FFF + ((u >> 16) & 1)) >> 16;
  return (ushort_t)u;
}
__device__ __forceinline__ float bf_lo(uint_t p) {
  return __builtin_bit_cast(float, p << 16);
}
__device__ __forceinline__ float bf_hi(uint_t p) {
  return __builtin_bit_cast(float, p & 0xFFFF0000u);
}
__device__ __forceinline__ uint4 pack8(float4 lo, float4 hi) {
  ushort_t t[8];
  t[0] = f2bf(lo.x); t[1] = f2bf(lo.y); t[2] = f2bf(lo.z); t[3] = f2bf(lo.w);
  t[4] = f2bf(hi.x); t[5] = f2bf(hi.y); t[6] = f2bf(hi.z); t[7] = f2bf(hi.w);
  return *(uint4*)t;
}

// pack one task of W (fp32, K x 128) into bf16 B-fragment order, K padded
// with zeros to KB*32. task in [0, 8*KB*64). P idx = task*8 + j.
__device__ __forceinline__ void pack_tile(const float* __restrict__ W,
                                          ushort_t* __restrict__ P, int KF,
                                          int KB, int task) {
  int t = task / (KB * 64);
  int rem = task - t * KB * 64;
  int kb = rem >> 6;
  int lane = rem & 63;
  int k0 = kb * 32 + ((lane >> 4) << 3);
  int c = t * 16 + (lane & 15);
  ushort_t tmp[8];
#pragma unroll
  for (int j = 0; j < 8; ++j) {
    int k = k0 + j;
    tmp[j] = (k < KF) ? f2bf(W[(size_t)k * HD + c]) : (ushort_t)0;
  }
  *(uint4*)(P + (size_t)task * 8) = *(uint4*)tmp;
}

// ---------------- prep: per-block bucket histogram + all W packs ----------
#define PACKB 46  // 4x8 (sage) + 8 (Wcomp K=128) + 6 (Wpol K=96)
__global__ __launch_bounds__(256) void prep_k(
    const int* __restrict__ dst, int* __restrict__ hist2t,
    const float* __restrict__ Wl1, const float* __restrict__ Wr1,
    const float* __restrict__ Wl2, const float* __restrict__ Wr2,
    const float* __restrict__ W_comp, const float* __restrict__ W_pol,
    ushort_t* __restrict__ wl1p, ushort_t* __restrict__ wr1p,
    ushort_t* __restrict__ wl2p, ushort_t* __restrict__ wr2p,
    ushort_t* __restrict__ wcompp, ushort_t* __restrict__ wpolp) {
  __shared__ int hist[BKT];
  int blk = blockIdx.x;
  int tid = threadIdx.x;
  if (blk < BINB) {
    for (int t = tid; t < BKT; t += 256) hist[t] = 0;
    __syncthreads();
    int base = blk * 4096;
#pragma unroll
    for (int q = 0; q < 16; ++q) {
      int e = base + q * 256 + tid;
      if (e < NE) atomicAdd(&hist[dst[e] >> 8], 1);
    }
    __syncthreads();
    for (int t = tid; t < BKT; t += 256)
      hist2t[(size_t)t * BINB + blk] = hist[t];
    return;
  }
  int pb = blk - BINB;
  if (pb < 8) pack_tile(Wl1, wl1p, 128, 4, pb * 256 + tid);
  else if (pb < 16) pack_tile(Wr1, wr1p, 128, 4, (pb - 8) * 256 + tid);
  else if (pb < 24) pack_tile(Wl2, wl2p, 128, 4, (pb - 16) * 256 + tid);
  else if (pb < 32) pack_tile(Wr2, wr2p, 128, 4, (pb - 24) * 256 + tid);
  else if (pb < 40) pack_tile(W_comp, wcompp, 112, 4, (pb - 32) * 256 + tid);
  else pack_tile(W_pol, wpolp, 72, 3, (pb - 40) * 256 + tid);
}

// ------- scanA: per-bucket exclusive prefix over blocks (wave scan) -------
__global__ __launch_bounds__(64) void scanA_k(int* __restrict__ hist2t,
                                              int* __restrict__ bcnt) {
  int t = blockIdx.x;
  int lane = threadIdx.x;
  int* base = hist2t + (size_t)t * BINB;
  int carry = 0;
  for (int c = 0; c < 7; ++c) {  // 7*64 = 448 >= BINB
    int i = c * 64 + lane;
    int orig = (i < BINB) ? base[i] : 0;
    int v = orig;
#pragma unroll
    for (int off = 1; off < 64; off <<= 1) {
      int u = __shfl_up(v, off);
      if (lane >= off) v += u;
    }
    if (i < BINB) base[i] = v - orig + carry;
    carry += __shfl(v, 63);
  }
  if (lane == 0) bcnt[t] = carry;
}

// ---------------- scanB: exclusive scan of bucket totals ----------------
__global__ __launch_bounds__(512) void scan_k(const int* __restrict__ bcnt,
                                              int* __restrict__ bstart) {
  __shared__ int s[512];
  int t = threadIdx.x;
  int v = (t < BKT) ? bcnt[t] : 0;
  s[t] = v;
  __syncthreads();
  for (int off = 1; off < 512; off <<= 1) {
    int x = (t >= off) ? s[t - off] : 0;
    __syncthreads();
    s[t] += x;
    __syncthreads();
  }
  if (t < BKT) bstart[t] = s[t] - v;
}

// ---------------- bin edges + MFMA encoders (fused, independent) -----------
// R7 lesson: keep the staged LDS sort (dropping it cost +9 us via
// uncoalesced 4B ebuf scatters). Deterministic gbase (R4, no bfill atomics).
#define COMP_E (NC / 128)        // 625 blocks, 128 nodes each
#define POL_E ((NP + 127) / 128) // 157
__global__ __launch_bounds__(512) void bin_enc_k(
    const int* __restrict__ src, const int* __restrict__ dst,
    const int* __restrict__ bstart, const int* __restrict__ hist2t,
    uint_t* __restrict__ ebuf,
    const float* __restrict__ x_comp, const int* __restrict__ sec,
    const int* __restrict__ ind, const float* __restrict__ semb,
    const float* __restrict__ iemb, const ushort_t* __restrict__ wcompp,
    const float* __restrict__ b_comp,
    const float* __restrict__ x_pol, const int* __restrict__ sidx,
    const float* __restrict__ stemb, const ushort_t* __restrict__ wpolp,
    const float* __restrict__ b_pol,
    ushort_t* __restrict__ h0) {
  __shared__ int hist[BKT];
  __shared__ int lscan[BKT];
  __shared__ int gbase[BKT];
  __shared__ int sv[512];
  __shared__ uint2 stage[4096];
  int blk = blockIdx.x;
  int tid = threadIdx.x;

  if (blk < BINB) {
    // ---- counting-sort 4096 edges into bucket-grouped ebuf ----
    for (int t = tid; t < BKT; t += 512) hist[t] = 0;
    __syncthreads();
    int base = blk * 4096;
    int cntE = min(4096, NE - base);
    int ss[8], dd[8], rr[8];
#pragma unroll
    for (int q = 0; q < 8; ++q) {
      int e = base + q * 512 + tid;
      if (e < NE) {
        dd[q] = dst[e];
        ss[q] = src[e];
        rr[q] = atomicAdd(&hist[dd[q] >> 8], 1);
      } else {
        dd[q] = -1;
      }
    }
    __syncthreads();
    int hv = (tid < BKT) ? hist[tid] : 0;
    sv[tid] = hv;
    __syncthreads();
    for (int off = 1; off < 512; off <<= 1) {
      int x = (tid >= off) ? sv[tid - off] : 0;
      __syncthreads();
      sv[tid] += x;
      __syncthreads();
    }
    if (tid < BKT) {
      lscan[tid] = sv[tid] - hv;
      gbase[tid] = bstart[tid] + hist2t[(size_t)tid * BINB + blk];
    }
    __syncthreads();
#pragma unroll
    for (int q = 0; q < 8; ++q) {
      if (dd[q] >= 0) {
        int bb = dd[q] >> 8;
        stage[lscan[bb] + rr[q]] = make_uint2((uint_t)ss[q], (uint_t)dd[q]);
      }
    }
    __syncthreads();
    for (int j = tid; j < cntE; j += 512) {
      uint2 v = stage[j];
      int bb = v.y >> 8;
      ebuf[gbase[bb] + (j - lscan[bb])] = (v.x << 8) | (v.y & 255u);
    }
    return;
  }
  int lane = tid & 63;
  int wv = tid >> 6;
  int n16 = lane & 15, quad = lane >> 4;
  if (blk < BINB + COMP_E) {
    // ---- comp encoder via MFMA: h = relu([x|sec|ind|0pad] @ Wc + bc) ----
    int rowbase = (blk - BINB) * 128 + wv * 16;
    int node = rowbase + n16;
    const float4* xr = (const float4*)(x_comp + (size_t)node * 96);
    uint4 a[4];
#pragma unroll
    for (int kb = 0; kb < 3; ++kb)
      a[kb] = pack8(xr[kb * 8 + quad * 2], xr[kb * 8 + quad * 2 + 1]);
    if (quad == 0) {
      const float4* er = (const float4*)(semb + (size_t)sec[node] * 8);
      a[3] = pack8(er[0], er[1]);
    } else if (quad == 1) {
      const float4* er = (const float4*)(iemb + (size_t)ind[node] * 8);
      a[3] = pack8(er[0], er[1]);
    } else {
      a[3] = make_uint4(0, 0, 0, 0);
    }
    const bf16x8* W = (const bf16x8*)wcompp;
    ushort_t* hb = h0 + (size_t)NP * HD;
#pragma unroll
    for (int t = 0; t < 8; ++t) {
      float bias = b_comp[t * 16 + n16];
      f32x4 acc = {bias, bias, bias, bias};
#pragma unroll
      for (int kb = 0; kb < 4; ++kb)
        acc = __builtin_amdgcn_mfma_f32_16x16x32_bf16(
            __builtin_bit_cast(bf16x8, a[kb]), W[(t * 4 + kb) * 64 + lane],
            acc, 0, 0, 0);
      int r0 = rowbase + quad * 4;
      int c = t * 16 + n16;
#pragma unroll
      for (int r = 0; r < 4; ++r)
        hb[(size_t)(r0 + r) * HD + c] = f2bf(fmaxf(acc[r], 0.f));
    }
    return;
  }
  {
    // ---- pol encoder via MFMA: h = relu([x|state|0pad] @ Wp + bp) ----
    int rowbase = (blk - BINB - COMP_E) * 128 + wv * 16;
    if (rowbase >= NP) return;
    int node = rowbase + n16;
    const float4* xr = (const float4*)(x_pol + (size_t)node * 64);
    uint4 a[3];
#pragma unroll
    for (int kb = 0; kb < 2; ++kb)
      a[kb] = pack8(xr[kb * 8 + quad * 2], xr[kb * 8 + quad * 2 + 1]);
    if (quad == 0) {
      const float4* er = (const float4*)(stemb + (size_t)sidx[node] * 8);
      a[2] = pack8(er[0], er[1]);
    } else {
      a[2] = make_uint4(0, 0, 0, 0);
    }
    const bf16x8* W = (const bf16x8*)wpolp;
#pragma unroll
    for (int t = 0; t < 8; ++t) {
      float bias = b_pol[t * 16 + n16];
      f32x4 acc = {bias, bias, bias, bias};
#pragma unroll
      for (int kb = 0; kb < 3; ++kb)
        acc = __builtin_amdgcn_mfma_f32_16x16x32_bf16(
            __builtin_bit_cast(bf16x8, a[kb]), W[(t * 3 + kb) * 64 + lane],
            acc, 0, 0, 0);
      int r0 = rowbase + quad * 4;
      int c = t * 16 + n16;
#pragma unroll
      for (int r = 0; r < 4; ++r)
        h0[(size_t)(r0 + r) * HD + c] = f2bf(fmaxf(acc[r], 0.f));
    }
  }
}

// ---------------- build: per-bucket L2-local CSR fill ----------------
__global__ __launch_bounds__(512) void build_k(const uint_t* __restrict__ ebuf,
                                               const int* __restrict__ bstart,
                                               const int* __restrict__ bcnt,
                                               int* __restrict__ col,
                                               int* __restrict__ cnt) {
  __shared__ int lcnt[256];
  int tid = threadIdx.x;
  int b = blockIdx.x;
  if (tid < 256) lcnt[tid] = 0;
  __syncthreads();
  int st = bstart[b];
  int cb = bcnt[b];
  for (int off = tid; off < cb; off += 512) {
    uint_t v = ebuf[st + off];
    int nl = v & 255u;
    int p = atomicAdd(&lcnt[nl], 1);
    if (p < MAXDEG) col[(size_t)((b << 8) | nl) * MAXDEG + p] = (int)(v >> 8);
  }
  __syncthreads();
  if (tid < 256) {
    int node = (b << 8) + tid;
    if (node < NN) cnt[node] = lcnt[tid];
  }
}

// ---------------- fused aggregate + SAGE (m never touches HBM) ------------
// R8 structure + LDS h-tile staging: waves 0-3 copy the block's own 16
// h-rows (4KB, contiguous, coalesced) into padded LDS at entry -- one
// upfront latency, transient registers only (R9's VGPR-hoist mistake
// avoided). Phase 2 reads am AND ah from LDS; its post-barrier global
// dependent chain is gone (only L2-hot W loads with 8-way ILP + MFMA).
__global__ __launch_bounds__(512) void agg_sage_k(
    const ushort_t* __restrict__ hbf, const int* __restrict__ cnt,
    const int* __restrict__ col, const ushort_t* __restrict__ Wlp,
    const float* __restrict__ bl, const ushort_t* __restrict__ Wrp,
    float* __restrict__ outf, ushort_t* __restrict__ outb, int relu) {
  __shared__ __align__(16) ushort_t lm[16][136];  // means (+8 pad)
  __shared__ __align__(16) ushort_t lh[16][136];  // own h rows (+8 pad)
  const uint4* hrow = (const uint4*)hbf;  // row = 16 uint4
  int tid = threadIdx.x;
  int lane = tid & 63;
  int wv = tid >> 6;                // 0..7
  int rowbase = blockIdx.x * 16;    // grid = NN/16 = 6250
  int grp = lane >> 4;  // 0..3: edge subgroup / quad
  int l16 = lane & 15;  // 16B chunk within row / n16

  // ---- stage own-h tile to LDS (waves 0-3; transient regs) ----
  if (tid < 256) {
    int row = tid >> 4, ch = tid & 15;
    uint4 g = hrow[(size_t)(rowbase + row) * 16 + ch];
    *(uint4*)&lh[row][ch * 8] = g;
  }
  float bias = bl[wv * 16 + l16];  // 1 VGPR, L2-hot

  // ---- phase 1: 2 nodes/wave gather (proven structure, 8 loads in flight) -
  int iA = rowbase + wv * 2;
  int iB = iA + 1;
  int dA = min(cnt[iA], MAXDEG);
  int dB = min(cnt[iB], MAXDEG);
  float accA[8] = {0.f, 0.f, 0.f, 0.f, 0.f, 0.f, 0.f, 0.f};
  float accB[8] = {0.f, 0.f, 0.f, 0.f, 0.f, 0.f, 0.f, 0.f};
  int mycA = (lane < dA) ? col[(size_t)iA * MAXDEG + lane] : 0;
  int mycB = (lane < dB) ? col[(size_t)iB * MAXDEG + lane] : 0;
  int nch = (max(dA, dB) + 15) >> 4;
  for (int ch = 0; ch < nch; ++ch) {
    int j0 = ch * 16;
    uint4 pA[4], pB[4];
    bool vA[4], vB[4];
#pragma unroll
    for (int q = 0; q < 4; ++q) {
      int e = j0 + q * 4 + grp;
      vA[q] = e < dA;
      int s = __shfl(mycA, vA[q] ? e : 0);
      pA[q] = hrow[(size_t)s * 16 + l16];
    }
#pragma unroll
    for (int q = 0; q < 4; ++q) {
      int e = j0 + q * 4 + grp;
      vB[q] = e < dB;
      int s = __shfl(mycB, vB[q] ? e : 0);
      pB[q] = hrow[(size_t)s * 16 + l16];
    }
#pragma unroll
    for (int q = 0; q < 4; ++q) {
      if (vA[q]) {
        accA[0] += bf_lo(pA[q].x); accA[1] += bf_hi(pA[q].x);
        accA[2] += bf_lo(pA[q].y); accA[3] += bf_hi(pA[q].y);
        accA[4] += bf_lo(pA[q].z); accA[5] += bf_hi(pA[q].z);
        accA[6] += bf_lo(pA[q].w); accA[7] += bf_hi(pA[q].w);
      }
      if (vB[q]) {
        accB[0] += bf_lo(pB[q].x); accB[1] += bf_hi(pB[q].x);
        accB[2] += bf_lo(pB[q].y); accB[3] += bf_hi(pB[q].y);
        accB[4] += bf_lo(pB[q].z); accB[5] += bf_hi(pB[q].z);
        accB[6] += bf_lo(pB[q].w); accB[7] += bf_hi(pB[q].w);
      }
    }
  }
#pragma unroll
  for (int k = 0; k < 8; ++k) {
    accA[k] += __shfl_xor(accA[k], 16);
    accA[k] += __shfl_xor(accA[k], 32);
    accB[k] += __shfl_xor(accB[k], 16);
    accB[k] += __shfl_xor(accB[k], 32);
  }
  if (grp == 0) {
    float inv = 1.f / (float)max(dA, 1);
    ushort_t t[8];
#pragma unroll
    for (int k = 0; k < 8; ++k) t[k] = f2bf(accA[k] * inv);
    *(uint4*)&lm[wv * 2][l16 * 8] = *(uint4*)t;
  } else if (grp == 1) {
    float inv = 1.f / (float)max(dB, 1);
    ushort_t t[8];
#pragma unroll
    for (int k = 0; k < 8; ++k) t[k] = f2bf(accB[k] * inv);
    *(uint4*)&lm[wv * 2 + 1][l16 * 8] = *(uint4*)t;
  }
  __syncthreads();

  // ---- phase 2: out[:, wv*16:(wv+1)*16] = [relu](m@Wl + bl + h@Wr) ----
  int t2 = wv;  // each wave owns one 16-col output slab
  int n16 = l16, quad = grp;
  uint4 am[4], ah[4];
#pragma unroll
  for (int kb = 0; kb < 4; ++kb) {
    am[kb] = *(const uint4*)&lm[n16][(kb * 4 + quad) * 8];
    ah[kb] = *(const uint4*)&lh[n16][(kb * 4 + quad) * 8];
  }
  const bf16x8* WL = (const bf16x8*)Wlp;
  const bf16x8* WR = (const bf16x8*)Wrp;
  f32x4 acc = {bias, bias, bias, bias};
#pragma unroll
  for (int kb = 0; kb < 4; ++kb)
    acc = __builtin_amdgcn_mfma_f32_16x16x32_bf16(
        __builtin_bit_cast(bf16x8, am[kb]), WL[(t2 * 4 + kb) * 64 + lane],
        acc, 0, 0, 0);
#pragma unroll
  for (int kb = 0; kb < 4; ++kb)
    acc = __builtin_amdgcn_mfma_f32_16x16x32_bf16(
        __builtin_bit_cast(bf16x8, ah[kb]), WR[(t2 * 4 + kb) * 64 + lane],
        acc, 0, 0, 0);
  int r0 = rowbase + quad * 4;
  int c = t2 * 16 + n16;
#pragma unroll
  for (int r = 0; r < 4; ++r) {
    float v = acc[r];
    if (relu) v = fmaxf(v, 0.f);
    if (outb)
      outb[(size_t)(r0 + r) * HD + c] = f2bf(v);
    else
      outf[(size_t)(r0 + r) * HD + c] = v;
  }
}

extern "C" void kernel_launch(void* const* d_in, const int* in_sizes, int n_in,
                              void* d_out, int out_size, void* d_ws,
                              size_t ws_size, hipStream_t stream) {
  const float* x_pol = (const float*)d_in[0];
  const int* pol_state_idx = (const int*)d_in[1];
  const float* x_comp = (const float*)d_in[2];
  const int* comp_sector = (const int*)d_in[3];
  const int* comp_ind = (const int*)d_in[4];
  const float* state_emb = (const float*)d_in[6];
  const float* sector_emb = (const float*)d_in[7];
  const float* ind_emb = (const float*)d_in[8];
  const float* W_pol = (const float*)d_in[9];
  const float* b_pol = (const float*)d_in[10];
  const float* W_comp = (const float*)d_in[11];
  const float* b_comp = (const float*)d_in[12];
  const float* Wl1 = (const float*)d_in[13];
  const float* bl1 = (const float*)d_in[14];
  const float* Wr1 = (const float*)d_in[15];
  const float* Wl2 = (const float*)d_in[16];
  const float* bl2 = (const float*)d_in[17];
  const float* Wr2 = (const float*)d_in[18];

  const int* src = (const int*)d_in[5];         // edge_index[0]
  const int* dst = ((const int*)d_in[5]) + NE;  // edge_index[1]

  // ws: h0_bf | h1_bf | col[NN*64] | ebuf[NE] | cnt[NN] |
  //     packed W x6 | bcnt | bstart | hist2t[391*391]   ~85 MB
  const size_t HBYTES = (size_t)NN * HD * sizeof(ushort_t);  // 25.6 MB
  char* ws = (char*)d_ws;
  ushort_t* h0_bf = (ushort_t*)ws;
  ushort_t* h1_bf = (ushort_t*)(ws + HBYTES);
  int* col = (int*)(ws + 2 * HBYTES);
  uint_t* ebuf = (uint_t*)(col + (size_t)NN * MAXDEG);
  int* cnt = (int*)(ebuf + NE);
  ushort_t* wl1p = (ushort_t*)(cnt + NN);  // 16384 elems each (K=128)
  ushort_t* wr1p = wl1p + 16384;
  ushort_t* wl2p = wr1p + 16384;
  ushort_t* wr2p = wl2p + 16384;
  ushort_t* wcompp = wr2p + 16384;   // 16384 (K padded to 128)
  ushort_t* wpolp = wcompp + 16384;  // 12288 (K padded to 96)
  int* bcnt = (int*)(wpolp + 12288);
  int* bstart = bcnt + BKT;
  int* hist2t = bstart + BKT;  // [BKT][BINB] = 611 KB

  float* out_f = (float*)d_out;

  // chain: per-block hist (no atomics) -> per-bucket block-prefix scan ->
  // bucket-total scan -> deterministic staged bin -> build
  prep_k<<<BINB + PACKB, 256, 0, stream>>>(dst, hist2t, Wl1, Wr1, Wl2, Wr2,
                                           W_comp, W_pol, wl1p, wr1p, wl2p,
                                           wr2p, wcompp, wpolp);
  scanA_k<<<BKT, 64, 0, stream>>>(hist2t, bcnt);
  scan_k<<<1, 512, 0, stream>>>(bcnt, bstart);
  bin_enc_k<<<BINB + COMP_E + POL_E, 512, 0, stream>>>(
      src, dst, bstart, hist2t, ebuf, x_comp, comp_sector, comp_ind,
      sector_emb, ind_emb, wcompp, b_comp, x_pol, pol_state_idx, state_emb,
      wpolp, b_pol, h0_bf);
  build_k<<<BKT, 512, 0, stream>>>(ebuf, bstart, bcnt, col, cnt);

  // layer 1: h1 = relu(mean-aggr(h0)@Wl1 + bl1 + h0@Wr1)  (bf16 out)
  agg_sage_k<<<NN / 16, 512, 0, stream>>>(h0_bf, cnt, col, wl1p, bl1, wr1p,
                                          nullptr, h1_bf, 1);
  // layer 2: out = mean-aggr(h1)@Wl2 + bl2 + h1@Wr2  (fp32 out)
  agg_sage_k<<<NN / 16, 512, 0, stream>>>(h1_bf, cnt, col, wl2p, bl2, wr2p,
                                          out_f, nullptr, 0);
}